// Round 3
// baseline (29.124 us; speedup 1.0000x reference)
//
#include <hip/hip_runtime.h>

// Neo-Hookean constants: E=1.0, nu=0.3
#define MU_NH  0.38461538461538464f
#define LAM_NH 0.5769230769230769f

typedef float f32x4 __attribute__((ext_vector_type(4)));  // native vec for nontemporal builtin

constexpr int TPB    = 256;        // threads per block
constexpr int MPB    = 1024;       // matrices per block
constexpr int NFLOAT = MPB * 9;    // 9216 floats = 36864 B LDS
constexpr int NVEC4  = NFLOAT / 4; // 2304 float4
constexpr int LOADS  = NVEC4 / TPB;    // 9 uniform float4 loads per thread
constexpr int MPT    = MPB / TPB;      // 4 matrices computed per thread

__global__ __launch_bounds__(TPB) void nh_potential_kernel(
    const float* __restrict__ x, float* __restrict__ out, int n)
{
    __shared__ float lds[NFLOAT];
    const int t = threadIdx.x;
    const int blockBase = blockIdx.x * MPB;            // first matrix index
    const int cnt = min(n - blockBase, MPB);           // matrices this block

    const float* src = x + (size_t)blockBase * 9;

    if (cnt == MPB) {
        // 9 perfectly coalesced, uniform float4 loads per thread (16 B/lane).
        // Streaming data: nontemporal hint avoids cache-allocate churn.
        const f32x4* src4 = reinterpret_cast<const f32x4*>(src);
        f32x4* lds4 = reinterpret_cast<f32x4*>(lds);
        #pragma unroll
        for (int i = 0; i < LOADS; ++i) {
            lds4[t + TPB * i] = __builtin_nontemporal_load(&src4[t + TPB * i]);
        }
    } else {
        // Tail block (4e6 % 1024 == 256): scalar staging, still coalesced.
        const int nflt = cnt * 9;
        for (int i = t; i < nflt; i += TPB) lds[i] = src[i];
    }
    __syncthreads();

    #pragma unroll
    for (int j = 0; j < MPT; ++j) {
        const int mi = t + TPB * j;
        if (mi < cnt) {
            // LDS read mi*9+k: gcd(9,32)=1 -> bank permutation, conflict-free.
            const float* m = &lds[mi * 9];
            const float a00 = m[0], a01 = m[1], a02 = m[2];
            const float a10 = m[3], a11 = m[4], a12 = m[5];
            const float a20 = m[6], a21 = m[7], a22 = m[8];

            // I1 = trace(x^T x) = sum of squares of all entries
            const float I1 = a00*a00 + a01*a01 + a02*a02
                           + a10*a10 + a11*a11 + a12*a12
                           + a20*a20 + a21*a21 + a22*a22;

            // J = det(x)
            const float J = a00 * (a11*a22 - a12*a21)
                          - a01 * (a10*a22 - a12*a20)
                          + a02 * (a10*a21 - a11*a20);

            const float logJ = __logf(J);  // ~1e-6 abs err near J=1, threshold 2.1e-3

            const float W = 0.5f * MU_NH * (I1 - 3.0f)
                          - MU_NH * logJ
                          + 0.5f * LAM_NH * logJ * logJ;

            __builtin_nontemporal_store(W, &out[blockBase + mi]);
        }
    }
}

extern "C" void kernel_launch(void* const* d_in, const int* in_sizes, int n_in,
                              void* d_out, int out_size, void* d_ws, size_t ws_size,
                              hipStream_t stream)
{
    const float* x = (const float*)d_in[0];
    float* out = (float*)d_out;
    const int n = in_sizes[0] / 9;                 // 4,000,000 matrices
    const int blocks = (n + MPB - 1) / MPB;        // 3907 (last block: 256 mats)
    nh_potential_kernel<<<blocks, TPB, 0, stream>>>(x, out, n);
}

// Round 4
// 28.779 us; speedup vs baseline: 1.0120x; 1.0120x over previous
//
#include <hip/hip_runtime.h>

// Neo-Hookean constants: E=1.0, nu=0.3
#define MU_NH  0.38461538461538464f
#define LAM_NH 0.5769230769230769f

typedef float f32x4 __attribute__((ext_vector_type(4)));  // native vec for nontemporal builtin

__global__ __launch_bounds__(256) void nh_potential_kernel(
    const float* __restrict__ x, float* __restrict__ out, int n)
{
    // 256 matrices / block = 9216 B LDS -> 8 blocks/CU, full 32 waves/CU.
    __shared__ float lds[256 * 9];
    const int t = threadIdx.x;
    const int blockBase = blockIdx.x * 256;
    const int cnt = min(n - blockBase, 256);

    const float* src = x + (size_t)blockBase * 9;

    if (cnt == 256) {
        // 2.25 coalesced float4 loads/thread (wave 0 does the extra quarter).
        const f32x4* src4 = reinterpret_cast<const f32x4*>(src);
        f32x4* lds4 = reinterpret_cast<f32x4*>(lds);
        lds4[t]       = __builtin_nontemporal_load(&src4[t]);
        lds4[t + 256] = __builtin_nontemporal_load(&src4[t + 256]);
        if (t < 64) lds4[t + 512] = __builtin_nontemporal_load(&src4[t + 512]);
    } else {
        const int nflt = cnt * 9;
        for (int i = t; i < nflt; i += 256) lds[i] = src[i];
    }
    __syncthreads();

    if (t < cnt) {
        // LDS read t*9+j: gcd(9,32)=1 -> bank permutation, conflict-free.
        const float* m = &lds[t * 9];
        const float a00 = m[0], a01 = m[1], a02 = m[2];
        const float a10 = m[3], a11 = m[4], a12 = m[5];
        const float a20 = m[6], a21 = m[7], a22 = m[8];

        // I1 = trace(x^T x) = sum of squares of all entries
        const float I1 = a00*a00 + a01*a01 + a02*a02
                       + a10*a10 + a11*a11 + a12*a12
                       + a20*a20 + a21*a21 + a22*a22;

        // J = det(x)
        const float J = a00 * (a11*a22 - a12*a21)
                      - a01 * (a10*a22 - a12*a20)
                      + a02 * (a10*a21 - a11*a20);

        const float logJ = __logf(J);  // ~1e-6 abs err near J=1, threshold 2.1e-3

        const float W = 0.5f * MU_NH * (I1 - 3.0f)
                      - MU_NH * logJ
                      + 0.5f * LAM_NH * logJ * logJ;

        __builtin_nontemporal_store(W, &out[blockBase + t]);
    }
}

extern "C" void kernel_launch(void* const* d_in, const int* in_sizes, int n_in,
                              void* d_out, int out_size, void* d_ws, size_t ws_size,
                              hipStream_t stream)
{
    const float* x = (const float*)d_in[0];
    float* out = (float*)d_out;
    const int n = in_sizes[0] / 9;              // 4,000,000 matrices
    const int blocks = (n + 255) / 256;         // 15625
    nh_potential_kernel<<<blocks, 256, 0, stream>>>(x, out, n);
}

// Round 5
// 27.957 us; speedup vs baseline: 1.0417x; 1.0294x over previous
//
#include <hip/hip_runtime.h>

// Neo-Hookean constants: E=1.0, nu=0.3
// MU  = E/(2(1+nu))            = 0.38461538461538464
// LAM = E*nu/((1+nu)(1-2nu))   = 0.5769230769230769
#define MU_NH  0.38461538461538464f
#define LAM_NH 0.5769230769230769f

__global__ __launch_bounds__(256) void nh_potential_kernel(
    const float* __restrict__ x, float* __restrict__ out, int n)
{
    // Stage 256 matrices (2304 floats = 9216 bytes) per block through LDS so
    // global loads are pure coalesced float4 (16 B/lane). 9216 % 16 == 0, so
    // every block's base is 16B-aligned. 9216 B LDS -> full 32 waves/CU.
    // NOTE: nontemporal load/store hints measured -3.5% here (R4 A/B) — keep
    // plain cached accesses.
    __shared__ float lds[256 * 9];
    const int t = threadIdx.x;
    const int blockBase = blockIdx.x * 256;           // first matrix index
    const int cnt = min(n - blockBase, 256);          // matrices this block

    const float* src = x + (size_t)blockBase * 9;

    if (cnt == 256) {
        const float4* src4 = reinterpret_cast<const float4*>(src);
        float4* lds4 = reinterpret_cast<float4*>(lds);
        lds4[t]       = src4[t];
        lds4[t + 256] = src4[t + 256];
        if (t < 64) lds4[t + 512] = src4[t + 512];
    } else {
        const int nflt = cnt * 9;
        for (int i = t; i < nflt; i += 256) lds[i] = src[i];
    }
    __syncthreads();

    if (t < cnt) {
        // LDS read t*9+j: gcd(9,32)=1 -> bank permutation, conflict-free.
        const float* m = &lds[t * 9];
        const float a00 = m[0], a01 = m[1], a02 = m[2];
        const float a10 = m[3], a11 = m[4], a12 = m[5];
        const float a20 = m[6], a21 = m[7], a22 = m[8];

        // I1 = trace(x^T x) = sum of squares of entries
        const float I1 = a00*a00 + a01*a01 + a02*a02
                       + a10*a10 + a11*a11 + a12*a12
                       + a20*a20 + a21*a21 + a22*a22;

        // J = det(x)
        const float J = a00 * (a11*a22 - a12*a21)
                      - a01 * (a10*a22 - a12*a20)
                      + a02 * (a10*a21 - a11*a20);

        const float logJ = __logf(J);   // v_log_f32-based; ~1e-6 abs err near J=1

        const float W = 0.5f * MU_NH * (I1 - 3.0f)
                      - MU_NH * logJ
                      + 0.5f * LAM_NH * logJ * logJ;

        out[blockBase + t] = W;
    }
}

extern "C" void kernel_launch(void* const* d_in, const int* in_sizes, int n_in,
                              void* d_out, int out_size, void* d_ws, size_t ws_size,
                              hipStream_t stream)
{
    const float* x = (const float*)d_in[0];
    float* out = (float*)d_out;
    const int n = in_sizes[0] / 9;                    // number of 3x3 matrices
    const int blocks = (n + 255) / 256;               // 15625 for B=4M
    nh_potential_kernel<<<blocks, 256, 0, stream>>>(x, out, n);
}